// Round 6
// baseline (368.847 us; speedup 1.0000x reference)
//
#include <hip/hip_runtime.h>
#include <math.h>

#define NG    64
#define NPG   2048
#define NTOT  (NG*NPG)     // 131072
#define ZD    64
#define PD    128
#define MH    256
#define NBLK  512

typedef __attribute__((ext_vector_type(8))) short bf16x8;
typedef __attribute__((ext_vector_type(4))) float f32x4;

// ---------- helpers ----------
__device__ __forceinline__ unsigned short f2bf(float f){
  unsigned u = __float_as_uint(f);
  unsigned r = u + 0x7FFFu + ((u >> 16) & 1u);
  return (unsigned short)(r >> 16);
}
__device__ __forceinline__ float bf2f(unsigned short s){
  return __uint_as_float(((unsigned)s) << 16);
}
// gelu via exp2+rcp (no IEEE div sequence) — verified bit-compatible round 2
__device__ __forceinline__ float gelu_f(float x){
  float u = x * x;
  float a = fmaf(0.044715f, u, 1.0f);
  float e = __builtin_amdgcn_exp2f(-2.3022083f * x * a);
  return x * __builtin_amdgcn_rcpf(1.0f + e);
}

// Software grid barrier (graph-capturable, unlike hipLaunchCooperativeKernel).
// Safe because grid=512 with 50176B static LDS => exactly 2 blocks/CU on all
// 256 CUs co-resident. __threadfence() on gfx950 = agent-scope fence (emits
// buffer_wbl2/buffer_inv) => cross-XCD visibility of prior normal stores.
__device__ __forceinline__ void gbar(int* bar, int target){
  __syncthreads();
  if (threadIdx.x == 0){
    __threadfence();
    atomicAdd(bar, 1);
    while (__hip_atomic_load(bar, __ATOMIC_RELAXED, __HIP_MEMORY_SCOPE_AGENT) < target)
      __builtin_amdgcn_s_sleep(2);
    __threadfence();
  }
  __syncthreads();
}

// ============================================================================
// Mega-kernel: phase A (pool + zstat) -> gbar -> phase B (stats) -> gbar ->
// phase C (lean MFMA final). 3 dispatches/iter total (fill + memset + this).
// ============================================================================
__launch_bounds__(256, 2)
__global__ void mega(const float* __restrict__ x, const float* __restrict__ z,
                     const float* __restrict__ W1, const float* __restrict__ b1,
                     const float* __restrict__ gamma, const float* __restrict__ beta,
                     const float* __restrict__ W2, const float* __restrict__ b2,
                     float* __restrict__ pooled, float* __restrict__ St,
                     float* __restrict__ C, float* __restrict__ Aj,
                     float* __restrict__ cp, unsigned short* __restrict__ Wbf,
                     float* __restrict__ out, int* __restrict__ bar){
  __shared__ __align__(16) unsigned char smem[50176];
  int tid = threadIdx.x;
  int bid = blockIdx.x;

  // ---------------- phase A: zstat (blocks 0..255) + pool units ----------------
  {
    unsigned short* s_zt = (unsigned short*)smem;       // 64*264 ushort = 33792 B
    float* s_cred = (float*)(smem + 33792);             // 4096 floats  = 16384 B

    if (bid < 256){
      // ---- zstat unit bid ----
      int g = bid >> 2, q4 = bid & 3;
      int lane = tid & 63, wave = tid >> 6;
      int col = lane & 15, quad = lane >> 4;
      const float4* z4 = (const float4*)z + ((size_t)g * 2048 + q4 * 512) * 16;
      int d4 = col;
      int mg = quad;

      f32x4 acc[4][4];
      #pragma unroll
      for (int a = 0; a < 4; a++)
        #pragma unroll
        for (int b = 0; b < 4; b++) acc[a][b] = (f32x4)(0.f);
      float s0 = 0.f, s1 = 0.f, s2 = 0.f, s3 = 0.f;

      for (int ch = 0; ch < 2; ch++){
        #pragma unroll
        for (int rd = 0; rd < 4; rd++){
          int m0 = rd * 64 + wave * 16 + mg * 4;
          const float4* src = z4 + ch * 4096 + m0 * 16 + d4;
          float4 v0 = src[0];
          float4 v1 = src[16];
          float4 v2 = src[32];
          float4 v3 = src[48];
          s0 += v0.x + v1.x + v2.x + v3.x;
          s1 += v0.y + v1.y + v2.y + v3.y;
          s2 += v0.z + v1.z + v2.z + v3.z;
          s3 += v0.w + v1.w + v2.w + v3.w;
          int slot = m0 >> 3;
          int sub  = m0 & 4;
          int d0 = d4 * 4;
          {
            int d = d0 + 0; int ss = slot ^ ((d >> 3) & 7);
            ushort4 w = make_ushort4(f2bf(v0.x), f2bf(v1.x), f2bf(v2.x), f2bf(v3.x));
            *(ushort4*)&s_zt[d * 264 + ss * 8 + sub] = w;
          }
          {
            int d = d0 + 1; int ss = slot ^ ((d >> 3) & 7);
            ushort4 w = make_ushort4(f2bf(v0.y), f2bf(v1.y), f2bf(v2.y), f2bf(v3.y));
            *(ushort4*)&s_zt[d * 264 + ss * 8 + sub] = w;
          }
          {
            int d = d0 + 2; int ss = slot ^ ((d >> 3) & 7);
            ushort4 w = make_ushort4(f2bf(v0.z), f2bf(v1.z), f2bf(v2.z), f2bf(v3.z));
            *(ushort4*)&s_zt[d * 264 + ss * 8 + sub] = w;
          }
          {
            int d = d0 + 3; int ss = slot ^ ((d >> 3) & 7);
            ushort4 w = make_ushort4(f2bf(v0.w), f2bf(v1.w), f2bf(v2.w), f2bf(v3.w));
            *(ushort4*)&s_zt[d * 264 + ss * 8 + sub] = w;
          }
        }
        __syncthreads();
        #pragma unroll
        for (int ks = 0; ks < 2; ks++){
          bf16x8 fr[4];
          #pragma unroll
          for (int t = 0; t < 4; t++){
            int row = t * 16 + col;
            int ss  = (wave * 8 + ks * 4 + quad) ^ ((row >> 3) & 7);
            fr[t] = *(const bf16x8*)&s_zt[row * 264 + ss * 8];
          }
          #pragma unroll
          for (int mt = 0; mt < 4; mt++)
            #pragma unroll
            for (int nt = 0; nt < 4; nt++)
              acc[mt][nt] = __builtin_amdgcn_mfma_f32_16x16x32_bf16(fr[mt], fr[nt], acc[mt][nt], 0, 0, 0);
        }
        __syncthreads();
      }

      s0 += __shfl_xor(s0, 16); s0 += __shfl_xor(s0, 32);
      s1 += __shfl_xor(s1, 16); s1 += __shfl_xor(s1, 32);
      s2 += __shfl_xor(s2, 16); s2 += __shfl_xor(s2, 32);
      s3 += __shfl_xor(s3, 16); s3 += __shfl_xor(s3, 32);
      if (quad == 0){
        atomicAdd(&St[(d4 * 4 + 0) * 64 + g], s0);
        atomicAdd(&St[(d4 * 4 + 1) * 64 + g], s1);
        atomicAdd(&St[(d4 * 4 + 2) * 64 + g], s2);
        atomicAdd(&St[(d4 * 4 + 3) * 64 + g], s3);
      }

      #pragma unroll
      for (int w = 0; w < 4; w++){
        if (wave == w){
          #pragma unroll
          for (int mt = 0; mt < 4; mt++)
            #pragma unroll
            for (int nt = 0; nt < 4; nt++)
              #pragma unroll
              for (int r = 0; r < 4; r++){
                int p = mt * 16 + quad * 4 + r;
                int qc = nt * 16 + col;
                if (w == 0) s_cred[p * 64 + qc]  = acc[mt][nt][r];
                else        s_cred[p * 64 + qc] += acc[mt][nt][r];
              }
        }
        __syncthreads();
      }
      for (int f = tid; f < 4096; f += 256)
        atomicAdd(&C[f], s_cred[f]);
    }

    // ---- pool units ----
    // blocks 0..255: unit bid; blocks 256..511: units bid, bid+256, bid+512
    int u0 = bid, nu = (bid < 256) ? 1 : 3;
    for (int k = 0; k < nu; k++){
      int bi = u0 + k * 256;          // 0..1023
      int b  = bi >> 4;
      int oh = bi & 15;
      int c4 = tid & 63;
      int rq = tid >> 6;
      const float4* x4 = (const float4*)x;
      size_t base = (size_t)(b * NPG + oh * 128) * 64;
      float4 acc = make_float4(0.f, 0.f, 0.f, 0.f);
      #pragma unroll 8
      for (int i = 0; i < 32; i++){
        float4 v = x4[base + (size_t)(rq + i * 4) * 64 + c4];
        acc.x += v.x; acc.y += v.y; acc.z += v.z; acc.w += v.w;
      }
      __syncthreads();               // protect s_cred reuse (zstat tail / prev unit)
      s_cred[tid] = acc.x + acc.y + acc.z + acc.w;
      __syncthreads();
      if (tid < 8){
        float s = 0.f;
        #pragma unroll
        for (int w = 0; w < 4; w++)
          #pragma unroll
          for (int j = 0; j < 8; j++)
            s += s_cred[w * 64 + tid * 8 + j];
        pooled[b * PD + oh * 8 + tid] = s * (1.0f / 4096.0f);
      }
    }
  }
  gbar(bar, NBLK);

  // ---------------- phase B: k2 stats on blocks 0..63 ----------------
  if (bid < 64){
    float* pl = (float*)smem;        // 64*129 floats = 33024 B
    int jc = tid >> 6, lane = tid & 63;
    int j = bid * 4 + jc;

    Wbf[(size_t)j * 64 + lane] = f2bf(W1[(size_t)lane * 256 + j]);

    for (int idx = tid; idx < 8192; idx += 256)
      pl[(idx >> 7) * 129 + (idx & 127)] = pooled[idx];
    __syncthreads();

    float g = b1[j];
    #pragma unroll 8
    for (int k = 0; k < 128; k++)
      g = fmaf(pl[lane * 129 + k], W1[(size_t)(ZD + k) * MH + j], g);

    float wl = W1[(size_t)lane * MH + j];
    float t1 = 0.f, t2 = 0.f;
    #pragma unroll
    for (int q = 0; q < 64; q++){
      float wq = __uint_as_float(__builtin_amdgcn_readlane(__float_as_uint(wl), q));
      t1 = fmaf(C [q * 64 + lane], wq, t1);
      t2 = fmaf(St[q * 64 + lane], wq, t2);
    }
    float v_wcw = wl * t1;
    float v_gs  = g * t2;
    float v_s   = t2;
    float v_g   = g;
    float v_g2  = g * g;
    #pragma unroll
    for (int off = 32; off; off >>= 1){
      v_wcw += __shfl_xor(v_wcw, off);
      v_gs  += __shfl_xor(v_gs , off);
      v_s   += __shfl_xor(v_s  , off);
      v_g   += __shfl_xor(v_g  , off);
      v_g2  += __shfl_xor(v_g2 , off);
    }
    const float invN = 1.0f / (float)NTOT;
    float mean = v_s * invN + v_g * (1.0f / 64.0f);
    float eh2  = v_wcw * invN + 2.0f * invN * v_gs + v_g2 * (1.0f / 64.0f);
    float var  = eh2 - mean * mean;
    float aj = gamma[j] * rsqrtf(var + 1e-5f);
    if (lane == 0) Aj[j] = aj;
    cp[lane * MH + j] = fmaf(aj, g, beta[j] - aj * mean);
  }
  gbar(bar, 2 * NBLK);

  // ---------------- phase C: lean k3 (64 nodes x 256 j), 4 units/block ----------------
  {
    unsigned short* zt = (unsigned short*)smem;          // 64*136 ushort = 17408 B
    float* slab = (float*)(smem + 17408);                // 4*192 floats  =  3072 B
    int lane = tid & 63, wave = tid >> 6;
    int col = lane & 15, quad = lane >> 4;
    int nbase = wave * 64;          // each wave owns 64 j-columns

    for (int u = bid; u < 2048; u += NBLK){
      int n0 = u * 64;
      int g  = u >> 5;              // 32 units per graph

      // stage z tile hi/lo: 64 rows x 16 d4 = 1024 float4
      const float4* z4 = (const float4*)z + (size_t)n0 * 16;
      #pragma unroll
      for (int i = 0; i < 4; i++){
        int idx = tid + i * 256;
        int m = idx >> 4, d4 = idx & 15;
        float4 v = z4[idx];
        ushort4 h, l;
        h.x = f2bf(v.x); l.x = f2bf(v.x - bf2f(h.x));
        h.y = f2bf(v.y); l.y = f2bf(v.y - bf2f(h.y));
        h.z = f2bf(v.z); l.z = f2bf(v.z - bf2f(h.z));
        h.w = f2bf(v.w); l.w = f2bf(v.w - bf2f(h.w));
        *(ushort4*)&zt[m * 136 + d4 * 4]      = h;
        *(ushort4*)&zt[m * 136 + 64 + d4 * 4] = l;
      }
      __syncthreads();

      f32x4 acc[4][4];
      #pragma unroll
      for (int mt = 0; mt < 4; mt++)
        #pragma unroll
        for (int nt = 0; nt < 4; nt++) acc[mt][nt] = (f32x4)(0.f);

      #pragma unroll
      for (int ks = 0; ks < 4; ks++){
        int k0 = ks * 32;           // A: k over 0..127 (hi|lo); B: (ks&1)*32
        bf16x8 af[4];
        #pragma unroll
        for (int mt = 0; mt < 4; mt++)
          af[mt] = *(const bf16x8*)&zt[(mt * 16 + col) * 136 + k0 + quad * 8];
        #pragma unroll
        for (int nt = 0; nt < 4; nt++){
          bf16x8 bv = *(const bf16x8*)&Wbf[(size_t)(nbase + nt * 16 + col) * 64 + (ks & 1) * 32 + quad * 8];
          #pragma unroll
          for (int mt = 0; mt < 4; mt++)
            acc[mt][nt] = __builtin_amdgcn_mfma_f32_16x16x32_bf16(af[mt], bv, acc[mt][nt], 0, 0, 0);
        }
      }

      float aj[4], cj[4], w2a[4], w2b[4], w2c[4];
      #pragma unroll
      for (int nt = 0; nt < 4; nt++){
        int j = nbase + nt * 16 + col;
        aj[nt] = Aj[j];
        cj[nt] = cp[g * MH + j];
        w2a[nt] = W2[j * 3 + 0];
        w2b[nt] = W2[j * 3 + 1];
        w2c[nt] = W2[j * 3 + 2];
      }

      #pragma unroll
      for (int mt = 0; mt < 4; mt++){
        #pragma unroll
        for (int r = 0; r < 4; r++){
          float o0 = 0.f, o1 = 0.f, o2 = 0.f;
          #pragma unroll
          for (int nt = 0; nt < 4; nt++){
            float h  = fmaf(aj[nt], acc[mt][nt][r], cj[nt]);
            float ge = gelu_f(h);
            o0 = fmaf(ge, w2a[nt], o0);
            o1 = fmaf(ge, w2b[nt], o1);
            o2 = fmaf(ge, w2c[nt], o2);
          }
          #pragma unroll
          for (int off = 8; off; off >>= 1){
            o0 += __shfl_xor(o0, off);
            o1 += __shfl_xor(o1, off);
            o2 += __shfl_xor(o2, off);
          }
          if (col == 0){
            int node = mt * 16 + quad * 4 + r;   // 0..63
            slab[wave * 192 + node * 3 + 0] = o0;
            slab[wave * 192 + node * 3 + 1] = o1;
            slab[wave * 192 + node * 3 + 2] = o2;
          }
        }
      }
      __syncthreads();
      if (tid < 192){
        float b2v = b2[tid % 3];
        out[(size_t)u * 192 + tid] = slab[tid] + slab[192 + tid] + slab[384 + tid] + slab[576 + tid] + b2v;
      }
      __syncthreads();   // slab/zt reuse vs next unit's staging
    }
  }
}

// ---------- launch ----------
extern "C" void kernel_launch(void* const* d_in, const int* in_sizes, int n_in,
                              void* d_out, int out_size, void* d_ws, size_t ws_size,
                              hipStream_t stream){
  (void)in_sizes; (void)n_in; (void)out_size; (void)ws_size;
  const float* x     = (const float*)d_in[0];
  const float* z     = (const float*)d_in[2];
  const float* W1    = (const float*)d_in[3];
  const float* b1    = (const float*)d_in[4];
  const float* gamma = (const float*)d_in[5];
  const float* beta  = (const float*)d_in[6];
  const float* W2    = (const float*)d_in[7];
  const float* b2    = (const float*)d_in[8];
  float* out = (float*)d_out;

  float* W = (float*)d_ws;
  float* pooled = W;                         // 0     .. 8191
  float* St     = W + 8192;                  // 8192  .. 12287
  float* C      = W + 12288;                 // 12288 .. 16383
  int*   bar    = (int*)(W + 16384);         // 16384 .. 16447 (padded)
  float* Aj     = W + 16448;                 // 16448 .. 16703
  float* CP     = W + 16704;                 // 16704 .. 33087
  unsigned short* Wbf = (unsigned short*)(W + 33088);  // 16384 ushorts

  // zero St + C + barrier counter (contiguous 33 KB)
  hipMemsetAsync((char*)d_ws + 8192 * 4, 0, (4096 + 4096 + 64) * 4, stream);

  mega<<<dim3(NBLK), dim3(256), 0, stream>>>(x, z, W1, b1, gamma, beta, W2, b2,
                                             pooled, St, C, Aj, CP, Wbf, out, bar);
}

// Round 7
// 309.976 us; speedup vs baseline: 1.1899x; 1.1899x over previous
//
#include <hip/hip_runtime.h>
#include <math.h>

#define NG    64
#define NPG   2048
#define NTOT  (NG*NPG)     // 131072
#define ZD    64
#define PD    128
#define MH    256

typedef __attribute__((ext_vector_type(8))) short bf16x8;
typedef __attribute__((ext_vector_type(4))) float f32x4;

// ---------- helpers ----------
__device__ __forceinline__ unsigned short f2bf(float f){
  unsigned u = __float_as_uint(f);
  unsigned r = u + 0x7FFFu + ((u >> 16) & 1u);
  return (unsigned short)(r >> 16);
}
__device__ __forceinline__ float bf2f(unsigned short s){
  return __uint_as_float(((unsigned)s) << 16);
}
// gelu via exp2+rcp (no IEEE div sequence) — verified bit-compatible round 2
__device__ __forceinline__ float gelu_f(float x){
  float u = x * x;
  float a = fmaf(0.044715f, u, 1.0f);
  float e = __builtin_amdgcn_exp2f(-2.3022083f * x * a);
  return x * __builtin_amdgcn_rcpf(1.0f + e);
}

// ---------- K1: fused pool (blocks 256..1279) + zstat (blocks 0..255) ----------
// Identical to proven round-5 kernel EXCEPT: C atomics spread over 8 partial
// buffers C8[8][4096] (contention /8, channel spread x8 — round-6 diagnosis:
// 1M device atomics on a 16KB region ~= 30us of channel-serialized RMWs),
// and block 1279 zeroes the k23 grid-barrier counter.
__launch_bounds__(256)
__global__ void k1_pool_zstat(const float* __restrict__ x, const float* __restrict__ z,
                              float* __restrict__ pooled, float* __restrict__ St,
                              float* __restrict__ C8, int* __restrict__ bar){
  __shared__ __align__(16) unsigned short s_zt[64 * 264];  // 33792 B, [d][m] swizzled
  __shared__ float s_cred[4096];                           // 16384 B (pool reuses first 256)
  int tid = threadIdx.x;

  if (blockIdx.x >= 256){
    if (blockIdx.x == 1279 && tid == 0) *bar = 0;   // init k23 barrier (k1 completes first)
    // ---- pool ----
    int bi = blockIdx.x - 256;
    int b  = bi >> 4;
    int oh = bi & 15;
    int c4 = tid & 63;
    int rq = tid >> 6;
    const float4* x4 = (const float4*)x;
    size_t base = (size_t)(b * NPG + oh * 128) * 64;
    float4 acc = make_float4(0.f, 0.f, 0.f, 0.f);
    #pragma unroll 8
    for (int i = 0; i < 32; i++){
      float4 v = x4[base + (size_t)(rq + i * 4) * 64 + c4];
      acc.x += v.x; acc.y += v.y; acc.z += v.z; acc.w += v.w;
    }
    s_cred[tid] = acc.x + acc.y + acc.z + acc.w;
    __syncthreads();
    if (tid < 8){
      float s = 0.f;
      #pragma unroll
      for (int w = 0; w < 4; w++)
        #pragma unroll
        for (int j = 0; j < 8; j++)
          s += s_cred[w * 64 + tid * 8 + j];
      pooled[b * PD + oh * 8 + tid] = s * (1.0f / 4096.0f);
    }
    return;
  }

  // ---- zstat ----
  int blk = blockIdx.x;           // 0..255
  int g = blk >> 2, q4 = blk & 3;
  int lane = tid & 63, wave = tid >> 6;
  int col = lane & 15, quad = lane >> 4;
  const float4* z4 = (const float4*)z + ((size_t)g * 2048 + q4 * 512) * 16;
  int d4 = col;
  int mg = quad;

  f32x4 acc[4][4];
  #pragma unroll
  for (int a = 0; a < 4; a++)
    #pragma unroll
    for (int b = 0; b < 4; b++) acc[a][b] = (f32x4)(0.f);
  float s0 = 0.f, s1 = 0.f, s2 = 0.f, s3 = 0.f;

  for (int ch = 0; ch < 2; ch++){
    #pragma unroll
    for (int rd = 0; rd < 4; rd++){
      int m0 = rd * 64 + wave * 16 + mg * 4;
      const float4* src = z4 + ch * 4096 + m0 * 16 + d4;
      float4 v0 = src[0];
      float4 v1 = src[16];
      float4 v2 = src[32];
      float4 v3 = src[48];
      s0 += v0.x + v1.x + v2.x + v3.x;
      s1 += v0.y + v1.y + v2.y + v3.y;
      s2 += v0.z + v1.z + v2.z + v3.z;
      s3 += v0.w + v1.w + v2.w + v3.w;
      int slot = m0 >> 3;
      int sub  = m0 & 4;
      int d0 = d4 * 4;
      {
        int d = d0 + 0; int ss = slot ^ ((d >> 3) & 7);
        ushort4 w = make_ushort4(f2bf(v0.x), f2bf(v1.x), f2bf(v2.x), f2bf(v3.x));
        *(ushort4*)&s_zt[d * 264 + ss * 8 + sub] = w;
      }
      {
        int d = d0 + 1; int ss = slot ^ ((d >> 3) & 7);
        ushort4 w = make_ushort4(f2bf(v0.y), f2bf(v1.y), f2bf(v2.y), f2bf(v3.y));
        *(ushort4*)&s_zt[d * 264 + ss * 8 + sub] = w;
      }
      {
        int d = d0 + 2; int ss = slot ^ ((d >> 3) & 7);
        ushort4 w = make_ushort4(f2bf(v0.z), f2bf(v1.z), f2bf(v2.z), f2bf(v3.z));
        *(ushort4*)&s_zt[d * 264 + ss * 8 + sub] = w;
      }
      {
        int d = d0 + 3; int ss = slot ^ ((d >> 3) & 7);
        ushort4 w = make_ushort4(f2bf(v0.w), f2bf(v1.w), f2bf(v2.w), f2bf(v3.w));
        *(ushort4*)&s_zt[d * 264 + ss * 8 + sub] = w;
      }
    }
    __syncthreads();
    #pragma unroll
    for (int ks = 0; ks < 2; ks++){
      bf16x8 fr[4];
      #pragma unroll
      for (int t = 0; t < 4; t++){
        int row = t * 16 + col;
        int ss  = (wave * 8 + ks * 4 + quad) ^ ((row >> 3) & 7);
        fr[t] = *(const bf16x8*)&s_zt[row * 264 + ss * 8];
      }
      #pragma unroll
      for (int mt = 0; mt < 4; mt++)
        #pragma unroll
        for (int nt = 0; nt < 4; nt++)
          acc[mt][nt] = __builtin_amdgcn_mfma_f32_16x16x32_bf16(fr[mt], fr[nt], acc[mt][nt], 0, 0, 0);
    }
    __syncthreads();
  }

  s0 += __shfl_xor(s0, 16); s0 += __shfl_xor(s0, 32);
  s1 += __shfl_xor(s1, 16); s1 += __shfl_xor(s1, 32);
  s2 += __shfl_xor(s2, 16); s2 += __shfl_xor(s2, 32);
  s3 += __shfl_xor(s3, 16); s3 += __shfl_xor(s3, 32);
  if (quad == 0){
    atomicAdd(&St[(d4 * 4 + 0) * 64 + g], s0);
    atomicAdd(&St[(d4 * 4 + 1) * 64 + g], s1);
    atomicAdd(&St[(d4 * 4 + 2) * 64 + g], s2);
    atomicAdd(&St[(d4 * 4 + 3) * 64 + g], s3);
  }

  #pragma unroll
  for (int w = 0; w < 4; w++){
    if (wave == w){
      #pragma unroll
      for (int mt = 0; mt < 4; mt++)
        #pragma unroll
        for (int nt = 0; nt < 4; nt++)
          #pragma unroll
          for (int r = 0; r < 4; r++){
            int p = mt * 16 + quad * 4 + r;
            int qc = nt * 16 + col;
            if (w == 0) s_cred[p * 64 + qc]  = acc[mt][nt][r];
            else        s_cred[p * 64 + qc] += acc[mt][nt][r];
          }
    }
    __syncthreads();
  }
  float* Cp = C8 + (size_t)(blk & 7) * 4096;   // 8-way partial: contention /8
  for (int f = tid; f < 4096; f += 256)
    atomicAdd(&Cp[f], s_cred[f]);
}

// ---------- K23: phase B (stats, blocks 0..63) -> grid barrier -> phase C ----------
// Software grid barrier is safe: 512 blocks, LDS 33KB (<=4 blk/CU), VGPR<=256
// via launch_bounds(256,2) (>=2 blk/CU) => all 512 co-resident on 256 CUs.
__device__ __forceinline__ void gbar(int* bar, int target){
  __syncthreads();
  if (threadIdx.x == 0){
    __threadfence();
    atomicAdd(bar, 1);
    while (__hip_atomic_load(bar, __ATOMIC_RELAXED, __HIP_MEMORY_SCOPE_AGENT) < target)
      __builtin_amdgcn_s_sleep(16);
    __threadfence();
  }
  __syncthreads();
}

__launch_bounds__(256, 2)
__global__ void k23(const float* __restrict__ z, const float* __restrict__ pooled,
                    const float* __restrict__ W1, const float* __restrict__ b1,
                    const float* __restrict__ gamma, const float* __restrict__ beta,
                    const float* __restrict__ W2, const float* __restrict__ b2,
                    const float* __restrict__ C8, const float* __restrict__ St,
                    float* __restrict__ Aj, float* __restrict__ cp,
                    unsigned short* __restrict__ Wbf, float* __restrict__ out,
                    int* __restrict__ bar){
  __shared__ __align__(16) unsigned char smem[33024];
  int tid = threadIdx.x;
  int bid = blockIdx.x;

  // ---------------- phase B: stats on blocks 0..63 ----------------
  if (bid < 64){
    float* pl = (float*)smem;        // 64*129 floats = 33024 B
    int jc = tid >> 6, lane = tid & 63;
    int j = bid * 4 + jc;

    Wbf[(size_t)j * 64 + lane] = f2bf(W1[(size_t)lane * 256 + j]);

    for (int idx = tid; idx < 8192; idx += 256)
      pl[(idx >> 7) * 129 + (idx & 127)] = pooled[idx];
    __syncthreads();

    float g = b1[j];
    #pragma unroll 8
    for (int k = 0; k < 128; k++)
      g = fmaf(pl[lane * 129 + k], W1[(size_t)(ZD + k) * MH + j], g);

    // reduce the 8 C-partials into LDS (reuses pl region; gmat done)
    __syncthreads();
    float* s_C = (float*)smem;       // 4096 floats = 16 KB
    for (int i = tid; i < 4096; i += 256){
      float s = 0.f;
      #pragma unroll
      for (int b = 0; b < 8; b++) s += C8[(size_t)b * 4096 + i];
      s_C[i] = s;
    }
    __syncthreads();

    float wl = W1[(size_t)lane * MH + j];
    float t1 = 0.f, t2 = 0.f;
    #pragma unroll
    for (int q = 0; q < 64; q++){
      float wq = __uint_as_float(__builtin_amdgcn_readlane(__float_as_uint(wl), q));
      t1 = fmaf(s_C[q * 64 + lane], wq, t1);
      t2 = fmaf(St [q * 64 + lane], wq, t2);
    }
    float v_wcw = wl * t1;
    float v_gs  = g * t2;
    float v_s   = t2;
    float v_g   = g;
    float v_g2  = g * g;
    #pragma unroll
    for (int off = 32; off; off >>= 1){
      v_wcw += __shfl_xor(v_wcw, off);
      v_gs  += __shfl_xor(v_gs , off);
      v_s   += __shfl_xor(v_s  , off);
      v_g   += __shfl_xor(v_g  , off);
      v_g2  += __shfl_xor(v_g2 , off);
    }
    const float invN = 1.0f / (float)NTOT;
    float mean = v_s * invN + v_g * (1.0f / 64.0f);
    float eh2  = v_wcw * invN + 2.0f * invN * v_gs + v_g2 * (1.0f / 64.0f);
    float var  = eh2 - mean * mean;
    float aj = gamma[j] * rsqrtf(var + 1e-5f);
    if (lane == 0) Aj[j] = aj;
    cp[lane * MH + j] = fmaf(aj, g, beta[j] - aj * mean);
  }
  gbar(bar, 512);

  // ---------------- phase C: lean final (64 nodes x 256 j), 4 units/block ----------------
  {
    unsigned short* zt = (unsigned short*)smem;          // 64*136 ushort = 17408 B
    float* slab = (float*)(smem + 17408);                // 4*192 floats  =  3072 B
    int lane = tid & 63, wave = tid >> 6;
    int col = lane & 15, quad = lane >> 4;
    int nbase = wave * 64;          // each wave owns 64 j-columns

    // hoist unit-invariant operands (valid only AFTER gbar: Wbf/Aj from phase B)
    bf16x8 bfrag[2][4];
    #pragma unroll
    for (int p = 0; p < 2; p++)
      #pragma unroll
      for (int nt = 0; nt < 4; nt++)
        bfrag[p][nt] = *(const bf16x8*)&Wbf[(size_t)(nbase + nt * 16 + col) * 64 + p * 32 + quad * 8];
    float aj[4], w2a[4], w2b[4], w2c[4];
    #pragma unroll
    for (int nt = 0; nt < 4; nt++){
      int j = nbase + nt * 16 + col;
      aj[nt] = Aj[j];
      w2a[nt] = W2[j * 3 + 0];
      w2b[nt] = W2[j * 3 + 1];
      w2c[nt] = W2[j * 3 + 2];
    }
    float b2v = b2[tid % 3];

    for (int u = bid; u < 2048; u += 512){
      int n0 = u * 64;
      int g  = u >> 5;              // 32 units per graph

      const float4* z4 = (const float4*)z + (size_t)n0 * 16;
      __syncthreads();              // protect zt/slab vs previous unit
      #pragma unroll
      for (int i = 0; i < 4; i++){
        int idx = tid + i * 256;
        int m = idx >> 4, d4 = idx & 15;
        float4 v = z4[idx];
        ushort4 h, l;
        h.x = f2bf(v.x); l.x = f2bf(v.x - bf2f(h.x));
        h.y = f2bf(v.y); l.y = f2bf(v.y - bf2f(h.y));
        h.z = f2bf(v.z); l.z = f2bf(v.z - bf2f(h.z));
        h.w = f2bf(v.w); l.w = f2bf(v.w - bf2f(h.w));
        *(ushort4*)&zt[m * 136 + d4 * 4]      = h;
        *(ushort4*)&zt[m * 136 + 64 + d4 * 4] = l;
      }
      __syncthreads();

      f32x4 acc[4][4];
      #pragma unroll
      for (int mt = 0; mt < 4; mt++)
        #pragma unroll
        for (int nt = 0; nt < 4; nt++) acc[mt][nt] = (f32x4)(0.f);

      #pragma unroll
      for (int ks = 0; ks < 4; ks++){
        int k0 = ks * 32;
        bf16x8 af[4];
        #pragma unroll
        for (int mt = 0; mt < 4; mt++)
          af[mt] = *(const bf16x8*)&zt[(mt * 16 + col) * 136 + k0 + quad * 8];
        #pragma unroll
        for (int nt = 0; nt < 4; nt++){
          #pragma unroll
          for (int mt = 0; mt < 4; mt++)
            acc[mt][nt] = __builtin_amdgcn_mfma_f32_16x16x32_bf16(af[mt], bfrag[ks & 1][nt], acc[mt][nt], 0, 0, 0);
        }
      }

      float cj[4];
      #pragma unroll
      for (int nt = 0; nt < 4; nt++)
        cj[nt] = cp[g * MH + nbase + nt * 16 + col];

      #pragma unroll
      for (int mt = 0; mt < 4; mt++){
        #pragma unroll
        for (int r = 0; r < 4; r++){
          float o0 = 0.f, o1 = 0.f, o2 = 0.f;
          #pragma unroll
          for (int nt = 0; nt < 4; nt++){
            float h  = fmaf(aj[nt], acc[mt][nt][r], cj[nt]);
            float ge = gelu_f(h);
            o0 = fmaf(ge, w2a[nt], o0);
            o1 = fmaf(ge, w2b[nt], o1);
            o2 = fmaf(ge, w2c[nt], o2);
          }
          #pragma unroll
          for (int off = 8; off; off >>= 1){
            o0 += __shfl_xor(o0, off);
            o1 += __shfl_xor(o1, off);
            o2 += __shfl_xor(o2, off);
          }
          if (col == 0){
            int node = mt * 16 + quad * 4 + r;   // 0..63
            slab[wave * 192 + node * 3 + 0] = o0;
            slab[wave * 192 + node * 3 + 1] = o1;
            slab[wave * 192 + node * 3 + 2] = o2;
          }
        }
      }
      __syncthreads();
      if (tid < 192)
        out[(size_t)u * 192 + tid] = slab[tid] + slab[192 + tid] + slab[384 + tid] + slab[576 + tid] + b2v;
    }
  }
}

// ---------- launch ----------
extern "C" void kernel_launch(void* const* d_in, const int* in_sizes, int n_in,
                              void* d_out, int out_size, void* d_ws, size_t ws_size,
                              hipStream_t stream){
  (void)in_sizes; (void)n_in; (void)out_size; (void)ws_size;
  const float* x     = (const float*)d_in[0];
  const float* z     = (const float*)d_in[2];
  const float* W1    = (const float*)d_in[3];
  const float* b1    = (const float*)d_in[4];
  const float* gamma = (const float*)d_in[5];
  const float* beta  = (const float*)d_in[6];
  const float* W2    = (const float*)d_in[7];
  const float* b2    = (const float*)d_in[8];
  float* out = (float*)d_out;

  float* W = (float*)d_ws;
  float* pooled = W;                         // 0     .. 8191
  float* St     = W + 8192;                  // 8192  .. 12287
  float* C8     = W + 12288;                 // 12288 .. 45055  (8 x 4096)
  int*   bar    = (int*)(W + 45056);         // 45056 (zeroed by k1 block 1279)
  float* Aj     = W + 45120;                 // 45120 .. 45375
  float* CP     = W + 45376;                 // 45376 .. 61759
  unsigned short* Wbf = (unsigned short*)(W + 61760);  // 16384 ushorts

  // zero St + C8 (contiguous 144 KB); bar zeroed inside k1
  hipMemsetAsync((char*)d_ws + 8192 * 4, 0, (4096 + 8 * 4096) * 4, stream);

  k1_pool_zstat<<<dim3(1280), dim3(256), 0, stream>>>(x, z, pooled, St, C8, bar);
  k23<<<dim3(512), dim3(256), 0, stream>>>(z, pooled, W1, b1, gamma, beta, W2, b2,
                                           C8, St, Aj, CP, Wbf, out, bar);
}